// Round 3
// baseline (329.837 us; speedup 1.0000x reference)
//
#include <hip/hip_runtime.h>

#define NROWS 16384
#define DIM   1024
#define QSCALE 32.0f            // fp4 pre-scale 2^5
#define E8M0S  0x7A7A7A7Au      // 122 -> 2^-5 in every byte (both operands)

typedef int    v4i    __attribute__((ext_vector_type(4)));
typedef int    v8i    __attribute__((ext_vector_type(8)));
typedef float  f32x16 __attribute__((ext_vector_type(16)));

__device__ __forceinline__ void glds16(const void* g, void* l) {
    __builtin_amdgcn_global_load_lds(
        (const __attribute__((address_space(1))) void*)g,
        (__attribute__((address_space(3))) void*)l,
        16, 0, 0);
}

__device__ __forceinline__ float fexp2(float x) {
#if __has_builtin(__builtin_amdgcn_exp2f)
    return __builtin_amdgcn_exp2f(x);
#else
    return exp2f(x);
#endif
}
__device__ __forceinline__ float flog2(float x) {
#if __has_builtin(__builtin_amdgcn_logf)
    return __builtin_amdgcn_logf(x);
#else
    return log2f(x);
#endif
}

// fp4 e2m1 round-to-nearest encode of y (|y| clipped to 6).
__device__ __forceinline__ unsigned fp4_nib(float y) {
    unsigned s = (__float_as_uint(y) >> 31) << 3;
    float a = fminf(fabsf(y), 6.0f);
    unsigned c = (unsigned)(a >= 0.25f) + (unsigned)(a >= 0.75f) +
                 (unsigned)(a >= 1.25f) + (unsigned)(a >= 1.75f) +
                 (unsigned)(a >= 2.5f)  + (unsigned)(a >= 3.5f)  +
                 (unsigned)(a >= 5.0f);
    return c | s;
}

// Wave-per-row, grid-stride. Lane-interleaved float4 loads: every load
// instruction is a fully-coalesced 1KB wave transaction.
__global__ __launch_bounds__(256) void norm_fused(
    const float* __restrict__ img,
    const float* __restrict__ txt,
    unsigned char* __restrict__ imgQ,   // [NROWS][512] packed fp4
    unsigned char* __restrict__ txtQ,
    const float* __restrict__ lscale,
    const float* __restrict__ lbias,
    float* __restrict__ diagPart) {
    const int t    = threadIdx.x;
    const int lane = t & 63;
    const int wave = t >> 6;
    const int gw   = blockIdx.x * 4 + wave;   // 8192 waves total
    const float sc   = __expf(lscale[0]);
    const float bias = lbias[0];

    for (int row = gw; row < NROWS; row += 8192) {
        const float4* pi = (const float4*)(img + (size_t)row * DIM);
        const float4* pt = (const float4*)(txt + (size_t)row * DIM);
        float4 vi[4], vt[4];
        float ssi = 0.0f, sst = 0.0f, dot = 0.0f;
        #pragma unroll
        for (int j = 0; j < 4; ++j) {
            vi[j] = pi[lane + 64 * j];
            vt[j] = pt[lane + 64 * j];
            ssi += vi[j].x*vi[j].x + vi[j].y*vi[j].y + vi[j].z*vi[j].z + vi[j].w*vi[j].w;
            sst += vt[j].x*vt[j].x + vt[j].y*vt[j].y + vt[j].z*vt[j].z + vt[j].w*vt[j].w;
            dot += vi[j].x*vt[j].x + vi[j].y*vt[j].y + vi[j].z*vt[j].z + vi[j].w*vt[j].w;
        }
        #pragma unroll
        for (int off = 1; off < 64; off <<= 1) {
            ssi += __shfl_xor(ssi, off, 64);
            sst += __shfl_xor(sst, off, 64);
            dot += __shfl_xor(dot, off, 64);
        }
        const float ii = 1.0f / fmaxf(sqrtf(ssi), 1e-12f);
        const float it = 1.0f / fmaxf(sqrtf(sst), 1e-12f);
        if (lane == 0) diagPart[row] = -fmaf(sc, dot * ii * it, bias);

        const float qi = ii * QSCALE, qt = it * QSCALE;
        ushort* oi = (ushort*)(imgQ + (size_t)row * 512);
        ushort* ot = (ushort*)(txtQ + (size_t)row * 512);
        #pragma unroll
        for (int j = 0; j < 4; ++j) {
            unsigned p = fp4_nib(vi[j].x * qi)        | (fp4_nib(vi[j].y * qi) << 4) |
                         (fp4_nib(vi[j].z * qi) << 8) | (fp4_nib(vi[j].w * qi) << 12);
            unsigned q = fp4_nib(vt[j].x * qt)        | (fp4_nib(vt[j].y * qt) << 4) |
                         (fp4_nib(vt[j].z * qt) << 8) | (fp4_nib(vt[j].w * qt) << 12);
            oi[lane + 64 * j] = (ushort)p;
            ot[lane + 64 * j] = (ushort)q;
        }
    }
}

// MX-fp4 GEMM, 256x256 tile, 512 threads (8 waves as 2x4), BK=256 elems
// (128B rows), 4 K-tiles, double-buffered LDS (128 KB, 2 waves/SIMD).
//
// R3: m201-style phase-split schedule (T3+T4+T5).
//  - Tile start: issue all 8 glds for tile k+1 into buf[cur^1], then
//    s_waitcnt vmcnt(8) (tile k's loads landed; k+1's stay in flight
//    across all 4 phases — counted vmcnt, never 0 mid-loop) + s_barrier.
//  - 4 phases per tile, each: {6 ds_read (ks slice) ; s_barrier ;
//    lgkmcnt(0) ; sched_barrier(0) ; setprio(1) ; 8 MFMA ; setprio(0) ;
//    s_barrier}. Waves whose reads clear first MFMA while the LDS pipe
//    serves later waves -> pipes overlap (max, not sum).
//  Race ledger: overwrite-after-read gated by phase-3 lgkmcnt(0)+barrier;
//  read-after-write by vmcnt gate + tile-start barrier; vmcnt count exact
//  (8 loads/tile, in-order).
// LDS slot s of row r holds global chunk s ^ (r&7) ^ ((r>>4)&1) (measured
// zero-conflict scatter swizzle, unchanged).
__global__ __launch_bounds__(512, 2) void siglip_gemm(
    const unsigned char* __restrict__ A,
    const unsigned char* __restrict__ B,
    const float* __restrict__ lscale,
    const float* __restrict__ lbias,
    float* __restrict__ gemmPart)
{
    __shared__ unsigned char sA[2][256 * 128];  // 2 x 32 KB
    __shared__ unsigned char sB[2][256 * 128];  // 2 x 32 KB
    __shared__ float wred[8];

    const int t    = threadIdx.x;
    const int lane = t & 63;
    const int wave = t >> 6;        // 0..7
    const int wr   = wave >> 2;     // 0..1 : A half (128 rows)
    const int wc   = wave & 3;      // 0..3 : B quarter (64 cols)
    const int r31  = lane & 31;
    const int h    = lane >> 5;     // k-half (32-elem MX block)
    const int xr   = (r31 & 7) ^ ((r31 >> 4) & 1);  // scatter row swizzle

    // XCD-bijective map (T1): each XCD keeps an 8-bcol B band (1 MB)
    // resident in its private L2 for the whole kernel; A streams through.
    // 4096 blocks = 8 xcd x 512 lb; bcol = xcd*8 + (lb&7), brow = lb>>3.
    const int b    = blockIdx.x;
    const int xcd  = b & 7;
    const int lb   = b >> 3;          // 0..511
    const int bcol = xcd * 8 + (lb & 7);   // 0..63
    const int brow = lb >> 3;              // 0..63

    const size_t aBase = (size_t)brow * 256;
    const size_t bBase = (size_t)bcol * 256;

    // Staging: glds16 = 1KB = 8 rows x 128B. lane -> (srow=l>>3, slot=l&7).
    // Wave w stages A rows [w*32, w*32+32) = 4 slabs; same for B.
    const int srow = lane >> 3;
    const int c0   = (lane & 7) ^ srow;
    const int d01  = (c0 & 1) ? -16 : 16;   // toggle chunk bit0 when (row>>4)&1

    const unsigned char* aP = A + (size_t)(aBase + wave * 32 + srow) * 512 + c0 * 16;
    const unsigned char* bP = B + (size_t)(bBase + wave * 32 + srow) * 512 + c0 * 16;

    int rbA[4], rbB[2];
    #pragma unroll
    for (int i = 0; i < 4; ++i) rbA[i] = (wr * 128 + i * 32 + r31) * 128;
    #pragma unroll
    for (int i = 0; i < 2; ++i) rbB[i] = (wc * 64 + i * 32 + r31) * 128;

    f32x16 acc[4][2] = {};

    // ---- prologue: stage K-tile 0 into buffer 0 ----
    {
        char* la = ((char*)sA[0]) + wave * 4096;
        char* lb_ = ((char*)sB[0]) + wave * 4096;
        #pragma unroll
        for (int j = 0; j < 4; ++j) {
            const int tog = ((j >> 1) & 1) ? d01 : 0;   // bit4 of row = (j>>1)&1
            glds16(aP + j * 8 * 512 + tog, la + j * 1024);
            glds16(bP + j * 8 * 512 + tog, lb_ + j * 1024);
        }
    }

    #pragma unroll
    for (int k = 0; k < 4; ++k) {
        const int cur = k & 1;      // compile-time under full unroll

        // ---- tile start: issue next tile's staging, gate this tile ----
        if (k < 3) {
            const unsigned char* aN = aP + (k + 1) * 128;
            const unsigned char* bN = bP + (k + 1) * 128;
            char* la = ((char*)sA[cur ^ 1]) + wave * 4096;
            char* lb_ = ((char*)sB[cur ^ 1]) + wave * 4096;
            #pragma unroll
            for (int j = 0; j < 4; ++j) {
                const int tog = ((j >> 1) & 1) ? d01 : 0;
                glds16(aN + j * 8 * 512 + tog, la + j * 1024);
                glds16(bN + j * 8 * 512 + tog, lb_ + j * 1024);
            }
            asm volatile("s_waitcnt vmcnt(8)" ::: "memory");  // tile k landed
        } else {
            asm volatile("s_waitcnt vmcnt(0)" ::: "memory");
        }
        __builtin_amdgcn_s_barrier();   // all waves' tile-k data visible

        // ---- 4 phases: {6 ds_read ; bar ; lgkm(0) ; 8 MFMA ; bar} ----
        #pragma unroll
        for (int ks = 0; ks < 4; ++ks) {
            const int s = ((ks * 2 + h) ^ xr) * 16;
            v4i av[4], bv[2];
            #pragma unroll
            for (int i = 0; i < 4; ++i)
                av[i] = *(const v4i*)(sA[cur] + rbA[i] + s);
            #pragma unroll
            for (int n = 0; n < 2; ++n)
                bv[n] = *(const v4i*)(sB[cur] + rbB[n] + s);

            __builtin_amdgcn_s_barrier();                    // phase align
            asm volatile("s_waitcnt lgkmcnt(0)" ::: "memory");
            __builtin_amdgcn_sched_barrier(0);               // rule 18
            __builtin_amdgcn_s_setprio(1);
            #pragma unroll
            for (int mi = 0; mi < 4; ++mi) {
                v8i a8 = __builtin_shufflevector(av[mi], av[mi],
                                                 0, 1, 2, 3, -1, -1, -1, -1);
                #pragma unroll
                for (int ni = 0; ni < 2; ++ni) {
                    v8i b8 = __builtin_shufflevector(bv[ni], bv[ni],
                                                     0, 1, 2, 3, -1, -1, -1, -1);
                    acc[mi][ni] = __builtin_amdgcn_mfma_scale_f32_32x32x64_f8f6f4(
                        a8, b8, acc[mi][ni],
                        4, 4,                     // cbsz=fp4(e2m1), blgp=fp4
                        0, (int)E8M0S,
                        0, (int)E8M0S);
                }
            }
            __builtin_amdgcn_s_setprio(0);
            __builtin_amdgcn_s_barrier();                    // phase end
        }
    }

    // Epilogue: softplus(z) over all elements (label=-1 form); diagonal fixed
    // by -z_ii. Group-of-4 log trick (t <= ~31, 4-term product < 2^125: safe).
    const float l2e   = 1.44269504088896341f;
    const float scale = __expf(lscale[0]);
    const float aCo   = scale * l2e;
    const float bCo   = lbias[0] * l2e;
    float local = 0.0f;
    #pragma unroll
    for (int mi = 0; mi < 4; ++mi)
        #pragma unroll
        for (int ni = 0; ni < 2; ++ni)
            #pragma unroll
            for (int r = 0; r < 16; r += 4) {
                float e0 = fexp2(fmaf(aCo, acc[mi][ni][r + 0], bCo));
                float e1 = fexp2(fmaf(aCo, acc[mi][ni][r + 1], bCo));
                float e2 = fexp2(fmaf(aCo, acc[mi][ni][r + 2], bCo));
                float e3 = fexp2(fmaf(aCo, acc[mi][ni][r + 3], bCo));
                float p  = ((1.0f + e0) * (1.0f + e1)) *
                           ((1.0f + e2) * (1.0f + e3));
                local += flog2(p);
            }

    #pragma unroll
    for (int off = 32; off > 0; off >>= 1) local += __shfl_down(local, off, 64);
    if (lane == 0) wred[wave] = local;
    __syncthreads();
    if (t == 0) {
        float tot = 0.0f;
        #pragma unroll
        for (int i = 0; i < 8; ++i) tot += wred[i];
        gemmPart[blockIdx.x] = tot * 0.69314718055994531f;
    }
}

// Sum 20480 partials (diagPart 16384 ++ gemmPart 4096, contiguous) -> loss.
__global__ __launch_bounds__(1024) void finalize_kernel(
    const float* __restrict__ parts, float* __restrict__ out) {
    __shared__ float wr[16];
    const int t    = threadIdx.x;
    const int lane = t & 63;
    const int wave = t >> 6;
    const float4* p4 = (const float4*)parts;   // 5120 float4
    float s = 0.0f;
    for (int i = t; i < 5120; i += 1024) {
        float4 v = p4[i];
        s += v.x + v.y + v.z + v.w;
    }
    #pragma unroll
    for (int off = 32; off > 0; off >>= 1) s += __shfl_down(s, off, 64);
    if (lane == 0) wr[wave] = s;
    __syncthreads();
    if (t == 0) {
        float tot = 0.0f;
        #pragma unroll
        for (int i = 0; i < 16; ++i) tot += wr[i];
        out[0] = tot / 268435456.0f;   // / N^2
    }
}

extern "C" void kernel_launch(void* const* d_in, const int* in_sizes, int n_in,
                              void* d_out, int out_size, void* d_ws, size_t ws_size,
                              hipStream_t stream) {
    const float* img    = (const float*)d_in[0];
    const float* txt    = (const float*)d_in[1];
    const float* lscale = (const float*)d_in[2];
    const float* lbias  = (const float*)d_in[3];
    float* out = (float*)d_out;

    char* ws = (char*)d_ws;
    unsigned char* imgQ = (unsigned char*)ws;                          // 8 MB
    unsigned char* txtQ = (unsigned char*)(ws + (size_t)NROWS * 512);  // 8 MB
    float* parts   = (float*)(ws + (size_t)2 * NROWS * 512);           // 20480 floats
    float* diagPart = parts;
    float* gemmPart = parts + NROWS;

    norm_fused<<<2048, 256, 0, stream>>>(img, txt, imgQ, txtQ, lscale, lbias, diagPart);
    siglip_gemm<<<dim3((NROWS / 256) * (NROWS / 256)), 512, 0, stream>>>(
        imgQ, txtQ, lscale, lbias, gemmPart);
    finalize_kernel<<<1, 1024, 0, stream>>>(parts, out);
}

// Round 4
// 312.684 us; speedup vs baseline: 1.0549x; 1.0549x over previous
//
#include <hip/hip_runtime.h>

#define NROWS 16384
#define DIM   1024
#define QSCALE 32.0f            // fp4 pre-scale 2^5
#define E8M0S  0x7A7A7A7Au      // 122 -> 2^-5 in every byte (both operands)

typedef int    v4i    __attribute__((ext_vector_type(4)));
typedef int    v8i    __attribute__((ext_vector_type(8)));
typedef float  f32x16 __attribute__((ext_vector_type(16)));

__device__ __forceinline__ void glds16(const void* g, void* l) {
    __builtin_amdgcn_global_load_lds(
        (const __attribute__((address_space(1))) void*)g,
        (__attribute__((address_space(3))) void*)l,
        16, 0, 0);
}

__device__ __forceinline__ float fexp2(float x) {
#if __has_builtin(__builtin_amdgcn_exp2f)
    return __builtin_amdgcn_exp2f(x);
#else
    return exp2f(x);
#endif
}
__device__ __forceinline__ float flog2(float x) {
#if __has_builtin(__builtin_amdgcn_logf)
    return __builtin_amdgcn_logf(x);
#else
    return log2f(x);
#endif
}

// fp4 e2m1 round-to-nearest encode of y (|y| clipped to 6).
__device__ __forceinline__ unsigned fp4_nib(float y) {
    unsigned s = (__float_as_uint(y) >> 31) << 3;
    float a = fminf(fabsf(y), 6.0f);
    unsigned c = (unsigned)(a >= 0.25f) + (unsigned)(a >= 0.75f) +
                 (unsigned)(a >= 1.25f) + (unsigned)(a >= 1.75f) +
                 (unsigned)(a >= 2.5f)  + (unsigned)(a >= 3.5f)  +
                 (unsigned)(a >= 5.0f);
    return c | s;
}

// Wave-per-row, grid-stride. Lane-interleaved float4 loads: every load
// instruction is a fully-coalesced 1KB wave transaction.
__global__ __launch_bounds__(256) void norm_fused(
    const float* __restrict__ img,
    const float* __restrict__ txt,
    unsigned char* __restrict__ imgQ,   // [NROWS][512] packed fp4
    unsigned char* __restrict__ txtQ,
    const float* __restrict__ lscale,
    const float* __restrict__ lbias,
    float* __restrict__ diagPart) {
    const int t    = threadIdx.x;
    const int lane = t & 63;
    const int wave = t >> 6;
    const int gw   = blockIdx.x * 4 + wave;   // 8192 waves total
    const float sc   = __expf(lscale[0]);
    const float bias = lbias[0];

    for (int row = gw; row < NROWS; row += 8192) {
        const float4* pi = (const float4*)(img + (size_t)row * DIM);
        const float4* pt = (const float4*)(txt + (size_t)row * DIM);
        float4 vi[4], vt[4];
        float ssi = 0.0f, sst = 0.0f, dot = 0.0f;
        #pragma unroll
        for (int j = 0; j < 4; ++j) {
            vi[j] = pi[lane + 64 * j];
            vt[j] = pt[lane + 64 * j];
            ssi += vi[j].x*vi[j].x + vi[j].y*vi[j].y + vi[j].z*vi[j].z + vi[j].w*vi[j].w;
            sst += vt[j].x*vt[j].x + vt[j].y*vt[j].y + vt[j].z*vt[j].z + vt[j].w*vt[j].w;
            dot += vi[j].x*vt[j].x + vi[j].y*vt[j].y + vi[j].z*vt[j].z + vi[j].w*vt[j].w;
        }
        #pragma unroll
        for (int off = 1; off < 64; off <<= 1) {
            ssi += __shfl_xor(ssi, off, 64);
            sst += __shfl_xor(sst, off, 64);
            dot += __shfl_xor(dot, off, 64);
        }
        const float ii = 1.0f / fmaxf(sqrtf(ssi), 1e-12f);
        const float it = 1.0f / fmaxf(sqrtf(sst), 1e-12f);
        if (lane == 0) diagPart[row] = -fmaf(sc, dot * ii * it, bias);

        const float qi = ii * QSCALE, qt = it * QSCALE;
        ushort* oi = (ushort*)(imgQ + (size_t)row * 512);
        ushort* ot = (ushort*)(txtQ + (size_t)row * 512);
        #pragma unroll
        for (int j = 0; j < 4; ++j) {
            unsigned p = fp4_nib(vi[j].x * qi)        | (fp4_nib(vi[j].y * qi) << 4) |
                         (fp4_nib(vi[j].z * qi) << 8) | (fp4_nib(vi[j].w * qi) << 12);
            unsigned q = fp4_nib(vt[j].x * qt)        | (fp4_nib(vt[j].y * qt) << 4) |
                         (fp4_nib(vt[j].z * qt) << 8) | (fp4_nib(vt[j].w * qt) << 12);
            oi[lane + 64 * j] = (ushort)p;
            ot[lane + 64 * j] = (ushort)q;
        }
    }
}

// MX-fp4 GEMM, 256x256 tile, 512 threads (8 waves as 2x4), BK=256 elems
// (128B rows), 4 K-tiles, double-buffered LDS (128 KB, 2 waves/SIMD).
//
// R4: intra-wave SLICE software pipeline with counted lgkmcnt.
//  Per K-tile: ONE barrier (buffer swap). Within the tile, 4 ks-slices:
//    issue 6 ds_read for slice ks+1 -> s_waitcnt lgkmcnt(6) (slice ks's 6
//    reads complete, DS in-order; the 6 new stay in flight under the MFMAs)
//    -> sched_barrier(0) (rule 18) -> 8 MFMA on slice ks.
//  LDS pipe services slice ks+1 DURING slice ks's MFMAs: per-slice time ~
//  max(576 LDS-cyc, 566 matrix-cyc), not sum. No per-phase barriers.
//  Race ledger: overwrite-after-read — each wave's slice-3 lgkmcnt(0)
//  precedes the tile barrier; glds for tile k+1 issue AFTER that barrier.
//  read-after-staging-write — vmcnt(0) gate BEFORE the barrier (all waves'
//  staging landed before anyone reads). glds lgkm-invisible (vmcnt only).
// LDS slot s of row r holds global chunk s ^ (r&7) ^ ((r>>4)&1) (measured
// zero-conflict scatter swizzle, unchanged).
__global__ __launch_bounds__(512, 2) void siglip_gemm(
    const unsigned char* __restrict__ A,
    const unsigned char* __restrict__ B,
    const float* __restrict__ lscale,
    const float* __restrict__ lbias,
    float* __restrict__ gemmPart)
{
    __shared__ unsigned char sA[2][256 * 128];  // 2 x 32 KB
    __shared__ unsigned char sB[2][256 * 128];  // 2 x 32 KB
    __shared__ float wred[8];

    const int t    = threadIdx.x;
    const int lane = t & 63;
    const int wave = t >> 6;        // 0..7
    const int wr   = wave >> 2;     // 0..1 : A half (128 rows)
    const int wc   = wave & 3;      // 0..3 : B quarter (64 cols)
    const int r31  = lane & 31;
    const int h    = lane >> 5;     // k-half (32-elem MX block)
    const int xr   = (r31 & 7) ^ ((r31 >> 4) & 1);  // scatter row swizzle

    // XCD-bijective map (T1): each XCD keeps an 8-bcol B band (1 MB)
    // resident in its private L2 for the whole kernel; A streams through.
    // Measured R3: FETCH 135 -> 37 MB. 4096 blocks = 8 xcd x 512 lb.
    const int b    = blockIdx.x;
    const int xcd  = b & 7;
    const int lb   = b >> 3;          // 0..511
    const int bcol = xcd * 8 + (lb & 7);   // 0..63
    const int brow = lb >> 3;              // 0..63

    const size_t aBase = (size_t)brow * 256;
    const size_t bBase = (size_t)bcol * 256;

    // Staging: glds16 = 1KB = 8 rows x 128B. lane -> (srow=l>>3, slot=l&7).
    // Wave w stages A rows [w*32, w*32+32) = 4 slabs; same for B.
    const int srow = lane >> 3;
    const int c0   = (lane & 7) ^ srow;
    const int d01  = (c0 & 1) ? -16 : 16;   // toggle chunk bit0 when (row>>4)&1

    const unsigned char* aP = A + (size_t)(aBase + wave * 32 + srow) * 512 + c0 * 16;
    const unsigned char* bP = B + (size_t)(bBase + wave * 32 + srow) * 512 + c0 * 16;

    int rbA[4], rbB[2];
    #pragma unroll
    for (int i = 0; i < 4; ++i) rbA[i] = (wr * 128 + i * 32 + r31) * 128;
    #pragma unroll
    for (int i = 0; i < 2; ++i) rbB[i] = (wc * 64 + i * 32 + r31) * 128;

    f32x16 acc[4][2] = {};

    // ---- prologue: stage K-tile 0 into buffer 0 ----
    {
        char* la = ((char*)sA[0]) + wave * 4096;
        char* lb_ = ((char*)sB[0]) + wave * 4096;
        #pragma unroll
        for (int j = 0; j < 4; ++j) {
            const int tog = ((j >> 1) & 1) ? d01 : 0;   // bit4 of row = (j>>1)&1
            glds16(aP + j * 8 * 512 + tog, la + j * 1024);
            glds16(bP + j * 8 * 512 + tog, lb_ + j * 1024);
        }
    }

    #pragma unroll
    for (int k = 0; k < 4; ++k) {
        const int cur = k & 1;      // compile-time under full unroll

        // ---- tile gate: staging for tile k landed, then swap barrier ----
        asm volatile("s_waitcnt vmcnt(0)" ::: "memory");
        __builtin_amdgcn_sched_barrier(0);
        __builtin_amdgcn_s_barrier();

        // ---- issue next tile's staging (buf[cur^1] is free now) ----
        if (k < 3) {
            const unsigned char* aN = aP + (k + 1) * 128;
            const unsigned char* bN = bP + (k + 1) * 128;
            char* la = ((char*)sA[cur ^ 1]) + wave * 4096;
            char* lb_ = ((char*)sB[cur ^ 1]) + wave * 4096;
            #pragma unroll
            for (int j = 0; j < 4; ++j) {
                const int tog = ((j >> 1) & 1) ? d01 : 0;
                glds16(aN + j * 8 * 512 + tog, la + j * 1024);
                glds16(bN + j * 8 * 512 + tog, lb_ + j * 1024);
            }
        }

        // ---- slice pipeline: read ks+1 under MFMA of ks ----
        v4i pa[2][4], pb[2][2];     // two slice reg-sets; indices static
        {
            const int s0 = (h ^ xr) * 16;
            #pragma unroll
            for (int i = 0; i < 4; ++i)
                pa[0][i] = *(const v4i*)(sA[cur] + rbA[i] + s0);
            #pragma unroll
            for (int n = 0; n < 2; ++n)
                pb[0][n] = *(const v4i*)(sB[cur] + rbB[n] + s0);
        }

        #pragma unroll
        for (int ks = 0; ks < 4; ++ks) {
            const int pc = ks & 1, pn = pc ^ 1;
            if (ks < 3) {
                const int s1 = (((ks + 1) * 2 + h) ^ xr) * 16;
                #pragma unroll
                for (int i = 0; i < 4; ++i)
                    pa[pn][i] = *(const v4i*)(sA[cur] + rbA[i] + s1);
                #pragma unroll
                for (int n = 0; n < 2; ++n)
                    pb[pn][n] = *(const v4i*)(sB[cur] + rbB[n] + s1);
                asm volatile("s_waitcnt lgkmcnt(6)" ::: "memory");
            } else {
                asm volatile("s_waitcnt lgkmcnt(0)" ::: "memory");
            }
            __builtin_amdgcn_sched_barrier(0);   // rule 18: pin MFMA after wait

            v8i a8[4], b8[2];
            #pragma unroll
            for (int i = 0; i < 4; ++i)
                a8[i] = __builtin_shufflevector(pa[pc][i], pa[pc][i],
                                                0, 1, 2, 3, -1, -1, -1, -1);
            #pragma unroll
            for (int n = 0; n < 2; ++n)
                b8[n] = __builtin_shufflevector(pb[pc][n], pb[pc][n],
                                                0, 1, 2, 3, -1, -1, -1, -1);

            __builtin_amdgcn_s_setprio(1);
            #pragma unroll
            for (int mi = 0; mi < 4; ++mi)
                #pragma unroll
                for (int ni = 0; ni < 2; ++ni)
                    acc[mi][ni] = __builtin_amdgcn_mfma_scale_f32_32x32x64_f8f6f4(
                        a8[mi], b8[ni], acc[mi][ni],
                        4, 4,                     // cbsz=fp4(e2m1), blgp=fp4
                        0, (int)E8M0S,
                        0, (int)E8M0S);
            __builtin_amdgcn_s_setprio(0);
        }
    }

    // Epilogue: softplus(z) over all elements (label=-1 form); diagonal fixed
    // by -z_ii. Group-of-4 log trick (t <= ~31, 4-term product < 2^125: safe).
    const float l2e   = 1.44269504088896341f;
    const float scale = __expf(lscale[0]);
    const float aCo   = scale * l2e;
    const float bCo   = lbias[0] * l2e;
    float local = 0.0f;
    #pragma unroll
    for (int mi = 0; mi < 4; ++mi)
        #pragma unroll
        for (int ni = 0; ni < 2; ++ni)
            #pragma unroll
            for (int r = 0; r < 16; r += 4) {
                float e0 = fexp2(fmaf(aCo, acc[mi][ni][r + 0], bCo));
                float e1 = fexp2(fmaf(aCo, acc[mi][ni][r + 1], bCo));
                float e2 = fexp2(fmaf(aCo, acc[mi][ni][r + 2], bCo));
                float e3 = fexp2(fmaf(aCo, acc[mi][ni][r + 3], bCo));
                float p  = ((1.0f + e0) * (1.0f + e1)) *
                           ((1.0f + e2) * (1.0f + e3));
                local += flog2(p);
            }

    #pragma unroll
    for (int off = 32; off > 0; off >>= 1) local += __shfl_down(local, off, 64);
    if (lane == 0) wred[wave] = local;
    __syncthreads();
    if (t == 0) {
        float tot = 0.0f;
        #pragma unroll
        for (int i = 0; i < 8; ++i) tot += wred[i];
        gemmPart[blockIdx.x] = tot * 0.69314718055994531f;
    }
}

// Sum 20480 partials (diagPart 16384 ++ gemmPart 4096, contiguous) -> loss.
__global__ __launch_bounds__(1024) void finalize_kernel(
    const float* __restrict__ parts, float* __restrict__ out) {
    __shared__ float wr[16];
    const int t    = threadIdx.x;
    const int lane = t & 63;
    const int wave = t >> 6;
    const float4* p4 = (const float4*)parts;   // 5120 float4
    float s = 0.0f;
    for (int i = t; i < 5120; i += 1024) {
        float4 v = p4[i];
        s += v.x + v.y + v.z + v.w;
    }
    #pragma unroll
    for (int off = 32; off > 0; off >>= 1) s += __shfl_down(s, off, 64);
    if (lane == 0) wr[wave] = s;
    __syncthreads();
    if (t == 0) {
        float tot = 0.0f;
        #pragma unroll
        for (int i = 0; i < 16; ++i) tot += wr[i];
        out[0] = tot / 268435456.0f;   // / N^2
    }
}

extern "C" void kernel_launch(void* const* d_in, const int* in_sizes, int n_in,
                              void* d_out, int out_size, void* d_ws, size_t ws_size,
                              hipStream_t stream) {
    const float* img    = (const float*)d_in[0];
    const float* txt    = (const float*)d_in[1];
    const float* lscale = (const float*)d_in[2];
    const float* lbias  = (const float*)d_in[3];
    float* out = (float*)d_out;

    char* ws = (char*)d_ws;
    unsigned char* imgQ = (unsigned char*)ws;                          // 8 MB
    unsigned char* txtQ = (unsigned char*)(ws + (size_t)NROWS * 512);  // 8 MB
    float* parts   = (float*)(ws + (size_t)2 * NROWS * 512);           // 20480 floats
    float* diagPart = parts;
    float* gemmPart = parts + NROWS;

    norm_fused<<<2048, 256, 0, stream>>>(img, txt, imgQ, txtQ, lscale, lbias, diagPart);
    siglip_gemm<<<dim3((NROWS / 256) * (NROWS / 256)), 512, 0, stream>>>(
        imgQ, txtQ, lscale, lbias, gemmPart);
    finalize_kernel<<<1, 1024, 0, stream>>>(parts, out);
}